// Round 14
// baseline (190.365 us; speedup 1.0000x reference)
//
#include <hip/hip_runtime.h>

#define BB 2
#define TT 2048
#define DD 1024
#define HH 16
#define DHD 64
#define MM (BB*TT)   // 4096

typedef __attribute__((ext_vector_type(8))) short short8;
typedef __attribute__((ext_vector_type(4))) float float4v;
typedef unsigned short u16;

__device__ inline float bf2f(u16 u) {
    union { unsigned int i; float f; } v;
    v.i = ((unsigned int)u) << 16;
    return v.f;
}
__device__ inline u16 f2bf(float f) {
    union { float f; unsigned int i; } v;
    v.f = f;
    unsigned int x = v.i;
    unsigned int r = (x + 0x7fffu + ((x >> 16) & 1u)) >> 16;
    return (u16)r;
}

// ---------------- prep: cast x to bf16 ----------------
__global__ __launch_bounds__(256) void cast_x_k(const float* __restrict__ x,
                                                u16* __restrict__ xb) {
    int i = blockIdx.x * 256 + threadIdx.x;   // 4 elems/thread
    float4v v = ((const float4v*)x)[i];
    ushort4 o;
    o.x = f2bf(v[0]); o.y = f2bf(v[1]); o.z = f2bf(v[2]); o.w = f2bf(v[3]);
    ((ushort4*)xb)[i] = o;
}

// ---------------- prep: cast + transpose weights (K,N)->(N,K) bf16 ----------------
__global__ __launch_bounds__(256) void transw_k(const float* __restrict__ Wq,
                                                const float* __restrict__ Wk,
                                                const float* __restrict__ Wv,
                                                const float* __restrict__ Wo,
                                                u16* __restrict__ WT) {
    __shared__ u16 t[32][33];
    int wsel = blockIdx.z;
    const float* W = (wsel == 0) ? Wq : (wsel == 1) ? Wk : (wsel == 2) ? Wv : Wo;
    u16* o = WT + (size_t)wsel * DD * DD;
    int k0 = blockIdx.y * 32, n0 = blockIdx.x * 32;
    int tx = threadIdx.x, ty = threadIdx.y;   // 32 x 8
#pragma unroll
    for (int i = 0; i < 4; i++) {
        int k = ty + i * 8;
        t[k][tx] = f2bf(W[(size_t)(k0 + k) * DD + n0 + tx]);
    }
    __syncthreads();
#pragma unroll
    for (int i = 0; i < 4; i++) {
        int n = ty + i * 8;
        o[(size_t)(n0 + n) * DD + k0 + tx] = t[tx][n];
    }
}

// ---------------- GEMM (r11 winner, unchanged): BK=64, XOR-swizzled, reg-prefetch ------------
template <int MODE, int TM, int TN>
__global__ __launch_bounds__(256) void gemm_k(const u16* __restrict__ A,
                                              const u16* __restrict__ WT0,
                                              void* __restrict__ outp) {
    const int K = DD, BK = 64;
    const int MT = TM / 32, NT = TN / 32;
    const int NS = (TM + TN) * (BK / 8) / 256;

    int z = blockIdx.z;
    const u16* WT = WT0 + (size_t)z * DD * DD;
    int n0 = blockIdx.x * TN, m0 = blockIdx.y * TM;

    __shared__ u16 S[(TM + TN) * BK];

    int tid = threadIdx.x;
    int lane = tid & 63, w = tid >> 6;
    int wm = (w >> 1) * (TM / 2), wn = (w & 1) * (TN / 2);
    int quad = lane >> 4, l16 = lane & 15;

    const u16* gp[NS];
    u16* lp[NS];
#pragma unroll
    for (int j = 0; j < NS; j++) {
        int cid = tid + j * 256;
        int r = cid >> 3, c = cid & 7;
        lp[j] = S + r * BK + (c ^ (r & 7)) * 8;
        gp[j] = (r < TM ? A + (size_t)(m0 + r) * K
                        : WT + (size_t)(n0 + r - TM) * K) + c * 8;
    }
    int swz = l16 & 7;

    float4v acc[MT][NT];
#pragma unroll
    for (int i = 0; i < MT; i++)
#pragma unroll
        for (int j = 0; j < NT; j++) acc[i][j] = (float4v)(0.0f);

    short8 pr[NS];
#pragma unroll
    for (int j = 0; j < NS; j++) pr[j] = *(const short8*)gp[j];

    const int NK = K / BK;
#pragma unroll 1
    for (int ki = 0; ki < NK; ki++) {
        __syncthreads();
#pragma unroll
        for (int j = 0; j < NS; j++) *(short8*)lp[j] = pr[j];
        __syncthreads();

        if (ki + 1 < NK) {
            int k0 = (ki + 1) * BK;
#pragma unroll
            for (int j = 0; j < NS; j++) pr[j] = *(const short8*)(gp[j] + k0);
        }

#pragma unroll
        for (int ks = 0; ks < 2; ks++) {
            int cq = ((ks * 4 + quad) ^ swz) * 8;
            short8 a[MT], b[NT];
#pragma unroll
            for (int mt = 0; mt < MT; mt++)
                a[mt] = *(const short8*)&S[(wm + mt * 16 + l16) * BK + cq];
#pragma unroll
            for (int nt = 0; nt < NT; nt++)
                b[nt] = *(const short8*)&S[(TM + wn + nt * 16 + l16) * BK + cq];
#pragma unroll
            for (int mt = 0; mt < MT; mt++)
#pragma unroll
                for (int nt = 0; nt < NT; nt++)
                    acc[mt][nt] = __builtin_amdgcn_mfma_f32_16x16x32_bf16(
                        a[mt], b[nt], acc[mt][nt], 0, 0, 0);
        }
    }

#pragma unroll
    for (int mt = 0; mt < MT; mt++) {
#pragma unroll
        for (int nt = 0; nt < NT; nt++) {
#pragma unroll
            for (int r = 0; r < 4; r++) {
                int m = m0 + wm + mt * 16 + quad * 4 + r;
                int n = n0 + wn + nt * 16 + l16;
                float v = acc[mt][nt][r];
                if constexpr (MODE == 0) {
                    int bb = m >> 11, t = m & 2047;
                    int h = n >> 6, dh = n & 63;
                    size_t idx;
                    if (z == 2)   // V stored transposed: (b,h,dh,t)
                        idx = (((size_t)2 * BB * HH + bb * HH + h) * DHD + dh) * TT + t;
                    else
                        idx = (((size_t)z * BB * HH + bb * HH + h) * TT + t) * DHD + dh;
                    ((u16*)outp)[idx] = f2bf(v);
                } else {
                    ((float*)outp)[(size_t)m * DD + n] = v;
                }
            }
        }
    }
}

// ---------------- flash attention: 256-thr block, 4 waves x 32q, merged pair ----------------
// attn is LDS-pipe bound (r13: 16 waves x 24 DS ops x ~9cy ~= measured 3360 cy/round).
// Fix: each wave covers 32 q rows -> K A-frags and V B-frags are REUSED across the
// two 16q sub-tiles, cutting DS reads per unit work 18 -> 10 b128. Waves 0-1 own
// q-tile p, waves 2-3 own q-tile 31-p (shared KV staging, rounds = 32-p).
// Constant-sum pairing p=(by&16)?15-t:t. All LDS unpadded 64-wide with the XOR
// chunk swizzle (0-conflict family, r8-r13). S^T trick + no-max softmax.
// Q staged through the Ps scratch (dead after prologue; barrier-hazard safe).
__global__ __launch_bounds__(256) void attn_k(const u16* __restrict__ QKV,
                                              u16* __restrict__ AO) {
    const u16* Q  = QKV;
    const u16* Kp = QKV + (size_t)MM * DD;
    const u16* Vp = QKV + (size_t)2 * MM * DD;   // V^T: per head [DHD][TT]
    int bh = blockIdx.y;
    int tswz = (blockIdx.x + blockIdx.y) & 15;
    int p = (blockIdx.y & 16) ? (15 - tswz) : tswz;
    int qA = p, qB = 31 - p;
    size_t hoff = (size_t)bh * TT * DHD;

    __shared__ u16 Ks[2][64 * 64];
    __shared__ u16 VTs[2][64 * 64];
    __shared__ u16 Ps[4][32 * 64];   // per-wave [32q][64kv]; doubles as Q staging (2x64x64)

    int tid = threadIdx.x;
    int lane = tid & 63, wv = tid >> 6;      // 4 waves
    int g = wv >> 1, h16 = wv & 1;           // group (tile), 32-row half
    int quad = lane >> 4, l16 = lane & 15;
    int cxs = l16 & 7;

    // staging: 2 chunks per thread per 64x64 tile (rows sr, sr+32)
    int sr = tid >> 3, sc = tid & 7;
    int swc = (sc ^ (sr & 7)) * 8;           // (sr+32)&7 == sr&7
    int sl0 = sr * 64 + swc, sl1 = (sr + 32) * 64 + swc;
    const u16* gK = Kp + hoff + (size_t)sr * DHD + sc * 8;
    const u16* gV = Vp + hoff + (size_t)sr * TT + sc * 8;

    u16* Qstage = &Ps[0][0];   // 16 KB: tile t at offset t*4096

    // stage both Q tiles, scaled by (1/sqrt(DH)) * log2(e)
    const float qscale = 0.125f * 1.4426950408889634f;
#pragma unroll
    for (int t = 0; t < 2; t++) {
        int q0 = (t ? qB : qA) * 64;
#pragma unroll
        for (int jj = 0; jj < 2; jj++) {
            int r = sr + jj * 32;
            short8 v = *(const short8*)(Q + hoff + (size_t)(q0 + r) * DHD + sc * 8);
            short8 sv;
#pragma unroll
            for (int e = 0; e < 8; e++) sv[e] = (short)f2bf(bf2f((u16)v[e]) * qscale);
            *(short8*)&Qstage[t * 4096 + r * 64 + swc] = sv;
        }
    }

    // prefetch KV tile 0
    short8 prK0 = *(const short8*)gK;
    short8 prK1 = *(const short8*)(gK + (size_t)32 * DHD);
    short8 prV0 = *(const short8*)gV;
    short8 prV1 = *(const short8*)(gV + (size_t)32 * TT);

    __syncthreads();   // Q staged
    // hoist Q B-frags: aq[qh][ks], rows h16*32 + qh*16 + l16 of tile g
    short8 aq[2][2];
#pragma unroll
    for (int qh = 0; qh < 2; qh++)
#pragma unroll
        for (int ks = 0; ks < 2; ks++)
            aq[qh][ks] = *(const short8*)&Qstage[g * 4096 +
                (h16 * 32 + qh * 16 + l16) * 64 + (((ks * 4 + quad) ^ cxs) * 8)];

    int myqt = g ? qB : qA;
    int ntile = myqt + 1;
    int NR = qB + 1;

    float4v o[2][4];
#pragma unroll
    for (int i = 0; i < 2; i++)
#pragma unroll
        for (int j = 0; j < 4; j++) o[i][j] = (float4v)(0.0f);
    float lr[2] = {0.0f, 0.0f};

#pragma unroll 1
    for (int jt = 0; jt < NR; jt++) {
        int db = jt & 1;
        *(short8*)&Ks[db][sl0]  = prK0;
        *(short8*)&Ks[db][sl1]  = prK1;
        *(short8*)&VTs[db][sl0] = prV0;
        *(short8*)&VTs[db][sl1] = prV1;
        __syncthreads();   // drains Q frag reads on jt==0; publishes tile db

        if (jt + 1 < NR) {
            size_t nj = (size_t)(jt + 1) * 64;
            prK0 = *(const short8*)(gK + nj * DHD);
            prK1 = *(const short8*)(gK + (nj + 32) * DHD);
            prV0 = *(const short8*)(gV + nj);
            prV1 = *(const short8*)(gV + (size_t)32 * TT + nj);
        }

        if (jt < ntile) {
            // S^T = K·Q^T: K A-frags shared across both q sub-tiles
            float4v s[2][4];
#pragma unroll
            for (int ct = 0; ct < 4; ct++) {
                int kr = (ct * 16 + l16) * 64;
                short8 ak0 = *(const short8*)&Ks[db][kr + ((quad ^ cxs) * 8)];
                short8 ak1 = *(const short8*)&Ks[db][kr + (((4 + quad) ^ cxs) * 8)];
#pragma unroll
                for (int qh = 0; qh < 2; qh++) {
                    float4v sv = (float4v)(0.0f);
                    sv = __builtin_amdgcn_mfma_f32_16x16x32_bf16(ak0, aq[qh][0], sv, 0, 0, 0);
                    sv = __builtin_amdgcn_mfma_f32_16x16x32_bf16(ak1, aq[qh][1], sv, 0, 0, 0);
                    s[qh][ct] = sv;   // lane: kv = ct*16+quad*4+r, q = qh*16+l16
                }
            }

            if (jt == myqt) {   // diagonal tile: mask kv > q (local coords)
#pragma unroll
                for (int qh = 0; qh < 2; qh++) {
                    int ql = h16 * 32 + qh * 16 + l16;
#pragma unroll
                    for (int ct = 0; ct < 4; ct++)
#pragma unroll
                        for (int r = 0; r < 4; r++) {
                            int kvl = ct * 16 + quad * 4 + r;
                            if (kvl > ql) s[qh][ct][r] = -30000.0f;
                        }
                }
            }

            // p = exp2(s); P write (C->A layout) swizzled b64 stores into Ps[wv]
#pragma unroll
            for (int qh = 0; qh < 2; qh++) {
#pragma unroll
                for (int ct = 0; ct < 4; ct++) {
                    float p0 = exp2f(s[qh][ct][0]);
                    float p1 = exp2f(s[qh][ct][1]);
                    float p2 = exp2f(s[qh][ct][2]);
                    float p3 = exp2f(s[qh][ct][3]);
                    lr[qh] += (p0 + p1) + (p2 + p3);
                    union { float f; unsigned u; } c0, c1, c2, c3;
                    c0.f = p0; c1.f = p1; c2.f = p2; c3.f = p3;
                    uint2 pw;
                    pw.x = __builtin_amdgcn_perm(c1.u, c0.u, 0x07060302u);
                    pw.y = __builtin_amdgcn_perm(c3.u, c2.u, 0x07060302u);
                    int chnk = (ct * 2 + (quad >> 1)) ^ cxs;
                    *(uint2*)&Ps[wv][(qh * 16 + l16) * 64 + chnk * 8 + (quad & 1) * 4] = pw;
                }
            }

            // PV: P A-frags per qh (shared across dh tiles), V B-frags shared across qh
            short8 ap[2][2];
#pragma unroll
            for (int qh = 0; qh < 2; qh++)
#pragma unroll
                for (int ks = 0; ks < 2; ks++)
                    ap[qh][ks] = *(const short8*)&Ps[wv][(qh * 16 + l16) * 64 +
                                                         (((ks * 4 + quad) ^ cxs) * 8)];
#pragma unroll
            for (int dt = 0; dt < 4; dt++) {
                int vr = (dt * 16 + l16) * 64;
                short8 bv0 = *(const short8*)&VTs[db][vr + ((quad ^ cxs) * 8)];
                short8 bv1 = *(const short8*)&VTs[db][vr + (((4 + quad) ^ cxs) * 8)];
#pragma unroll
                for (int qh = 0; qh < 2; qh++) {
                    o[qh][dt] = __builtin_amdgcn_mfma_f32_16x16x32_bf16(ap[qh][0], bv0, o[qh][dt], 0, 0, 0);
                    o[qh][dt] = __builtin_amdgcn_mfma_f32_16x16x32_bf16(ap[qh][1], bv1, o[qh][dt], 0, 0, 0);
                }
            }
        }
    }

    // row sums: lane holds partial for q = qh*16+l16; reduce across quads
    int b = bh >> 4, h = bh & 15;
    int q0 = myqt * 64;
    int gbase = lane & 48;
#pragma unroll
    for (int qh = 0; qh < 2; qh++) {
        float rs = lr[qh];
        rs += __shfl_xor(rs, 16);
        rs += __shfl_xor(rs, 32);
        float rinv[4];
#pragma unroll
        for (int r = 0; r < 4; r++)
            rinv[r] = 1.0f / __shfl(rs, gbase + quad * 4 + r);
#pragma unroll
        for (int dt = 0; dt < 4; dt++) {
#pragma unroll
            for (int r = 0; r < 4; r++) {
                int q = q0 + h16 * 32 + qh * 16 + quad * 4 + r;
                int d = h * 64 + dt * 16 + l16;
                AO[(size_t)(b * TT + q) * DD + d] = f2bf(o[qh][dt][r] * rinv[r]);
            }
        }
    }
}

extern "C" void kernel_launch(void* const* d_in, const int* in_sizes, int n_in,
                              void* d_out, int out_size, void* d_ws, size_t ws_size,
                              hipStream_t stream) {
    const float* x  = (const float*)d_in[0];
    const float* Wq = (const float*)d_in[1];
    const float* Wk = (const float*)d_in[2];
    const float* Wv = (const float*)d_in[3];
    const float* Wo = (const float*)d_in[4];

    u16* xb  = (u16*)d_ws;                       // 8 MB  : x in bf16
    u16* WT  = xb + (size_t)MM * DD;             // 8 MB  : 4 transposed weights bf16
    u16* QKV = WT + (size_t)4 * DD * DD;         // 24 MB : Q,K (b,h,t,dh) + V^T (b,h,dh,t)
    u16* AO  = QKV + (size_t)3 * MM * DD;        // 8 MB  : attention out (B,T,D) bf16
    float* out = (float*)d_out;

    cast_x_k<<<dim3(MM * DD / 1024), 256, 0, stream>>>(x, xb);
    transw_k<<<dim3(32, 32, 4), dim3(32, 8), 0, stream>>>(Wq, Wk, Wv, Wo, WT);
    gemm_k<0, 128, 128><<<dim3(DD / 128, MM / 128, 3), 256, 0, stream>>>(xb, WT, QKV);
    attn_k<<<dim3(16, 32), 256, 0, stream>>>(QKV, AO);
    gemm_k<1, 64, 128><<<dim3(DD / 128, MM / 64, 1), 256, 0, stream>>>(AO, WT + (size_t)3 * DD * DD, out);
}

// Round 15
// 177.447 us; speedup vs baseline: 1.0728x; 1.0728x over previous
//
#include <hip/hip_runtime.h>

#define BB 2
#define TT 2048
#define DD 1024
#define HH 16
#define DHD 64
#define MM (BB*TT)   // 4096

typedef __attribute__((ext_vector_type(8))) short short8;
typedef __attribute__((ext_vector_type(4))) float float4v;
typedef unsigned short u16;

__device__ inline float bf2f(u16 u) {
    union { unsigned int i; float f; } v;
    v.i = ((unsigned int)u) << 16;
    return v.f;
}
__device__ inline u16 f2bf(float f) {
    union { float f; unsigned int i; } v;
    v.f = f;
    unsigned int x = v.i;
    unsigned int r = (x + 0x7fffu + ((x >> 16) & 1u)) >> 16;
    return (u16)r;
}

// ---------------- prep: cast x to bf16 ----------------
__global__ __launch_bounds__(256) void cast_x_k(const float* __restrict__ x,
                                                u16* __restrict__ xb) {
    int i = blockIdx.x * 256 + threadIdx.x;   // 4 elems/thread
    float4v v = ((const float4v*)x)[i];
    ushort4 o;
    o.x = f2bf(v[0]); o.y = f2bf(v[1]); o.z = f2bf(v[2]); o.w = f2bf(v[3]);
    ((ushort4*)xb)[i] = o;
}

// ---------------- prep: cast + transpose weights (K,N)->(N,K) bf16 ----------------
__global__ __launch_bounds__(256) void transw_k(const float* __restrict__ Wq,
                                                const float* __restrict__ Wk,
                                                const float* __restrict__ Wv,
                                                const float* __restrict__ Wo,
                                                u16* __restrict__ WT) {
    __shared__ u16 t[32][33];
    int wsel = blockIdx.z;
    const float* W = (wsel == 0) ? Wq : (wsel == 1) ? Wk : (wsel == 2) ? Wv : Wo;
    u16* o = WT + (size_t)wsel * DD * DD;
    int k0 = blockIdx.y * 32, n0 = blockIdx.x * 32;
    int tx = threadIdx.x, ty = threadIdx.y;   // 32 x 8
#pragma unroll
    for (int i = 0; i < 4; i++) {
        int k = ty + i * 8;
        t[k][tx] = f2bf(W[(size_t)(k0 + k) * DD + n0 + tx]);
    }
    __syncthreads();
#pragma unroll
    for (int i = 0; i < 4; i++) {
        int n = ty + i * 8;
        o[(size_t)(n0 + n) * DD + k0 + tx] = t[tx][n];
    }
}

// ---------------- GEMM (r11 winner, unchanged): BK=64, XOR-swizzled, reg-prefetch ------------
template <int MODE, int TM, int TN>
__global__ __launch_bounds__(256) void gemm_k(const u16* __restrict__ A,
                                              const u16* __restrict__ WT0,
                                              void* __restrict__ outp) {
    const int K = DD, BK = 64;
    const int MT = TM / 32, NT = TN / 32;
    const int NS = (TM + TN) * (BK / 8) / 256;

    int z = blockIdx.z;
    const u16* WT = WT0 + (size_t)z * DD * DD;
    int n0 = blockIdx.x * TN, m0 = blockIdx.y * TM;

    __shared__ u16 S[(TM + TN) * BK];

    int tid = threadIdx.x;
    int lane = tid & 63, w = tid >> 6;
    int wm = (w >> 1) * (TM / 2), wn = (w & 1) * (TN / 2);
    int quad = lane >> 4, l16 = lane & 15;

    const u16* gp[NS];
    u16* lp[NS];
#pragma unroll
    for (int j = 0; j < NS; j++) {
        int cid = tid + j * 256;
        int r = cid >> 3, c = cid & 7;
        lp[j] = S + r * BK + (c ^ (r & 7)) * 8;
        gp[j] = (r < TM ? A + (size_t)(m0 + r) * K
                        : WT + (size_t)(n0 + r - TM) * K) + c * 8;
    }
    int swz = l16 & 7;

    float4v acc[MT][NT];
#pragma unroll
    for (int i = 0; i < MT; i++)
#pragma unroll
        for (int j = 0; j < NT; j++) acc[i][j] = (float4v)(0.0f);

    short8 pr[NS];
#pragma unroll
    for (int j = 0; j < NS; j++) pr[j] = *(const short8*)gp[j];

    const int NK = K / BK;
#pragma unroll 1
    for (int ki = 0; ki < NK; ki++) {
        __syncthreads();
#pragma unroll
        for (int j = 0; j < NS; j++) *(short8*)lp[j] = pr[j];
        __syncthreads();

        if (ki + 1 < NK) {
            int k0 = (ki + 1) * BK;
#pragma unroll
            for (int j = 0; j < NS; j++) pr[j] = *(const short8*)(gp[j] + k0);
        }

#pragma unroll
        for (int ks = 0; ks < 2; ks++) {
            int cq = ((ks * 4 + quad) ^ swz) * 8;
            short8 a[MT], b[NT];
#pragma unroll
            for (int mt = 0; mt < MT; mt++)
                a[mt] = *(const short8*)&S[(wm + mt * 16 + l16) * BK + cq];
#pragma unroll
            for (int nt = 0; nt < NT; nt++)
                b[nt] = *(const short8*)&S[(TM + wn + nt * 16 + l16) * BK + cq];
#pragma unroll
            for (int mt = 0; mt < MT; mt++)
#pragma unroll
                for (int nt = 0; nt < NT; nt++)
                    acc[mt][nt] = __builtin_amdgcn_mfma_f32_16x16x32_bf16(
                        a[mt], b[nt], acc[mt][nt], 0, 0, 0);
        }
    }

#pragma unroll
    for (int mt = 0; mt < MT; mt++) {
#pragma unroll
        for (int nt = 0; nt < NT; nt++) {
#pragma unroll
            for (int r = 0; r < 4; r++) {
                int m = m0 + wm + mt * 16 + quad * 4 + r;
                int n = n0 + wn + nt * 16 + l16;
                float v = acc[mt][nt][r];
                if constexpr (MODE == 0) {
                    int bb = m >> 11, t = m & 2047;
                    int h = n >> 6, dh = n & 63;
                    size_t idx;
                    if (z == 2)   // V stored transposed: (b,h,dh,t)
                        idx = (((size_t)2 * BB * HH + bb * HH + h) * DHD + dh) * TT + t;
                    else
                        idx = (((size_t)z * BB * HH + bb * HH + h) * TT + t) * DHD + dh;
                    ((u16*)outp)[idx] = f2bf(v);
                } else {
                    ((float*)outp)[(size_t)m * DD + n] = v;
                }
            }
        }
    }
}

// ---------------- flash attention: r12 skeleton + 2 KV tiles per barrier-round --------------
// r12 (512 thr, merged pair p / 31-p, 16 waves/CU) measured best at 43 us and is
// latency-bound (r14: halving waves -> 1.4x worse). Levers left at fixed 16 waves:
// fewer barriers + more in-wave ILP. Each round now stages 128 kv rows as two
// 64x64 sub-tiles (proven XOR-swizzle layout each) -> barrier-rounds/CU ~25 (was 49);
// sub-tile 1's S-MFMAs are independent of sub-tile 0's softmax->PV chain.
// No-max softmax (pure sums) makes tail sub-tiles safely skippable.
// Q staged through Ps scratch (dead after prologue). LDS = 80 KB -> 2 blocks/CU.
__global__ __launch_bounds__(512) void attn_k(const u16* __restrict__ QKV,
                                              u16* __restrict__ AO) {
    const u16* Q  = QKV;
    const u16* Kp = QKV + (size_t)MM * DD;
    const u16* Vp = QKV + (size_t)2 * MM * DD;   // V^T: per head [DHD][TT]
    int bh = blockIdx.y;
    int tswz = (blockIdx.x + blockIdx.y) & 15;
    int p = (blockIdx.y & 16) ? (15 - tswz) : tswz;
    int qA = p, qB = 31 - p;
    size_t hoff = (size_t)bh * TT * DHD;

    __shared__ u16 Ks[2][2][64 * 64];    // [dbuf][subtile]
    __shared__ u16 VTs[2][2][64 * 64];
    __shared__ u16 Ps[8][16 * 64];       // per-wave P scratch; doubles as Q staging

    int tid = threadIdx.x;
    int lane = tid & 63, wv = tid >> 6;      // 8 waves
    int g = wv >> 2, w4 = wv & 3;            // group (tile), 16-row block
    int quad = lane >> 4, l16 = lane & 15;
    int cxs = l16 & 7;

    // staging: one 16B chunk per thread per 64x64 sub-tile
    int sr = tid >> 3, sc = tid & 7;
    int sl = sr * 64 + ((sc ^ (sr & 7)) * 8);
    const u16* gK = Kp + hoff + (size_t)sr * DHD + sc * 8;
    const u16* gV = Vp + hoff + (size_t)sr * TT + sc * 8;

    u16* Qstage = &Ps[0][0];   // 16 KB: tile t at offset t*4096

    // stage both Q tiles, scaled by (1/sqrt(DH)) * log2(e)
    const float qscale = 0.125f * 1.4426950408889634f;
#pragma unroll
    for (int t = 0; t < 2; t++) {
        int q0 = (t ? qB : qA) * 64;
        short8 v = *(const short8*)(Q + hoff + (size_t)(q0 + sr) * DHD + sc * 8);
        short8 sv;
#pragma unroll
        for (int e = 0; e < 8; e++) sv[e] = (short)f2bf(bf2f((u16)v[e]) * qscale);
        *(short8*)&Qstage[t * 4096 + sl] = sv;
    }

    // prefetch KV round 0 (two sub-tiles)
    short8 prK[2], prV[2];
    prK[0] = *(const short8*)gK;
    prK[1] = *(const short8*)(gK + (size_t)64 * DHD);
    prV[0] = *(const short8*)gV;
    prV[1] = *(const short8*)(gV + 64);

    __syncthreads();   // Q staged
    int fr = w4 * 16 + l16;   // my q-row within my tile
    short8 aq0 = *(const short8*)&Qstage[g * 4096 + fr * 64 + ((quad ^ cxs) * 8)];
    short8 aq1 = *(const short8*)&Qstage[g * 4096 + fr * 64 + (((4 + quad) ^ cxs) * 8)];

    int myqt = g ? qB : qA;
    int NR = (qB + 2) >> 1;   // staged rounds (2 tiles each)

    float4v o[4];
#pragma unroll
    for (int i = 0; i < 4; i++) o[i] = (float4v)(0.0f);
    float lr = 0.0f;

#pragma unroll 1
    for (int jt = 0; jt < NR; jt++) {
        int db = jt & 1;
#pragma unroll
        for (int tt = 0; tt < 2; tt++) {
            *(short8*)&Ks[db][tt][sl]  = prK[tt];
            *(short8*)&VTs[db][tt][sl] = prV[tt];
        }
        __syncthreads();   // drains Q frag reads on jt==0; publishes round db

        if (jt + 1 < NR) {   // prefetch next 128-row round
            size_t nj = (size_t)(jt + 1) * 128;
            prK[0] = *(const short8*)(gK + nj * DHD);
            prK[1] = *(const short8*)(gK + (nj + 64) * DHD);
            prV[0] = *(const short8*)(gV + nj);
            prV[1] = *(const short8*)(gV + nj + 64);
        }

#pragma unroll
        for (int tt = 0; tt < 2; tt++) {
            int tj = 2 * jt + tt;
            if (tj <= myqt) {
                // S^T (64 kv x 16 q per wave) = K·Q^T
                float4v s[4];
#pragma unroll
                for (int ct = 0; ct < 4; ct++) {
                    int kr = (ct * 16 + l16) * 64;
                    short8 ak0 = *(const short8*)&Ks[db][tt][kr + ((quad ^ cxs) * 8)];
                    short8 ak1 = *(const short8*)&Ks[db][tt][kr + (((4 + quad) ^ cxs) * 8)];
                    float4v sv = (float4v)(0.0f);
                    sv = __builtin_amdgcn_mfma_f32_16x16x32_bf16(ak0, aq0, sv, 0, 0, 0);
                    sv = __builtin_amdgcn_mfma_f32_16x16x32_bf16(ak1, aq1, sv, 0, 0, 0);
                    s[ct] = sv;   // lane: kv = ct*16+quad*4+r, q = fr
                }

                if (tj == myqt) {   // diagonal tile: mask kv > q (local coords)
                    int ql = w4 * 16 + l16;
#pragma unroll
                    for (int ct = 0; ct < 4; ct++)
#pragma unroll
                        for (int r = 0; r < 4; r++) {
                            int kvl = ct * 16 + quad * 4 + r;
                            if (kvl > ql) s[ct][r] = -30000.0f;
                        }
                }

                // p = exp2(s); P write (C->A layout) swizzled 8B stores
#pragma unroll
                for (int ct = 0; ct < 4; ct++) {
                    float p0 = exp2f(s[ct][0]);
                    float p1 = exp2f(s[ct][1]);
                    float p2 = exp2f(s[ct][2]);
                    float p3 = exp2f(s[ct][3]);
                    lr += (p0 + p1) + (p2 + p3);
                    union { float f; unsigned u; } c0, c1, c2, c3;
                    c0.f = p0; c1.f = p1; c2.f = p2; c3.f = p3;
                    ushort4 pw;
                    pw.x = (u16)(c0.u >> 16);
                    pw.y = (u16)(c1.u >> 16);
                    pw.z = (u16)(c2.u >> 16);
                    pw.w = (u16)(c3.u >> 16);
                    int chnk = (ct * 2 + (quad >> 1)) ^ cxs;
                    *(ushort4*)&Ps[wv][l16 * 64 + chnk * 8 + (quad & 1) * 4] = pw;
                }

                short8 ap0 = *(const short8*)&Ps[wv][l16 * 64 + ((quad ^ cxs) * 8)];
                short8 ap1 = *(const short8*)&Ps[wv][l16 * 64 + (((4 + quad) ^ cxs) * 8)];
#pragma unroll
                for (int ct = 0; ct < 4; ct++) {
                    int vr = (ct * 16 + l16) * 64;
                    short8 bv0 = *(const short8*)&VTs[db][tt][vr + ((quad ^ cxs) * 8)];
                    short8 bv1 = *(const short8*)&VTs[db][tt][vr + (((4 + quad) ^ cxs) * 8)];
                    o[ct] = __builtin_amdgcn_mfma_f32_16x16x32_bf16(ap0, bv0, o[ct], 0, 0, 0);
                    o[ct] = __builtin_amdgcn_mfma_f32_16x16x32_bf16(ap1, bv1, o[ct], 0, 0, 0);
                }
            }
        }
    }

    // reduce row sums across quads (lane holds q = w4*16 + l16)
    float rs = lr;
    rs += __shfl_xor(rs, 16);
    rs += __shfl_xor(rs, 32);
    int gbase = lane & 48;
    float rinv[4];
#pragma unroll
    for (int r = 0; r < 4; r++)
        rinv[r] = 1.0f / __shfl(rs, gbase + quad * 4 + r);

    int b = bh >> 4, h = bh & 15;
    int q0 = myqt * 64;
#pragma unroll
    for (int ct = 0; ct < 4; ct++) {
#pragma unroll
        for (int r = 0; r < 4; r++) {
            int q = q0 + w4 * 16 + quad * 4 + r;
            int d = h * 64 + ct * 16 + l16;
            AO[(size_t)(b * TT + q) * DD + d] = f2bf(o[ct][r] * rinv[r]);
        }
    }
}

extern "C" void kernel_launch(void* const* d_in, const int* in_sizes, int n_in,
                              void* d_out, int out_size, void* d_ws, size_t ws_size,
                              hipStream_t stream) {
    const float* x  = (const float*)d_in[0];
    const float* Wq = (const float*)d_in[1];
    const float* Wk = (const float*)d_in[2];
    const float* Wv = (const float*)d_in[3];
    const float* Wo = (const float*)d_in[4];

    u16* xb  = (u16*)d_ws;                       // 8 MB  : x in bf16
    u16* WT  = xb + (size_t)MM * DD;             // 8 MB  : 4 transposed weights bf16
    u16* QKV = WT + (size_t)4 * DD * DD;         // 24 MB : Q,K (b,h,t,dh) + V^T (b,h,dh,t)
    u16* AO  = QKV + (size_t)3 * MM * DD;        // 8 MB  : attention out (B,T,D) bf16
    float* out = (float*)d_out;

    cast_x_k<<<dim3(MM * DD / 1024), 256, 0, stream>>>(x, xb);
    transw_k<<<dim3(32, 32, 4), dim3(32, 8), 0, stream>>>(Wq, Wk, Wv, Wo, WT);
    gemm_k<0, 128, 128><<<dim3(DD / 128, MM / 128, 3), 256, 0, stream>>>(xb, WT, QKV);
    attn_k<<<dim3(16, 32), 512, 0, stream>>>(QKV, AO);
    gemm_k<1, 64, 128><<<dim3(DD / 128, MM / 64, 1), 256, 0, stream>>>(AO, WT + (size_t)3 * DD * DD, out);
}

// Round 16
// 169.321 us; speedup vs baseline: 1.1243x; 1.0480x over previous
//
#include <hip/hip_runtime.h>

#define BB 2
#define TT 2048
#define DD 1024
#define HH 16
#define DHD 64
#define MM (BB*TT)   // 4096

typedef __attribute__((ext_vector_type(8))) short short8;
typedef __attribute__((ext_vector_type(4))) float float4v;
typedef unsigned short u16;

__device__ inline float bf2f(u16 u) {
    union { unsigned int i; float f; } v;
    v.i = ((unsigned int)u) << 16;
    return v.f;
}
__device__ inline u16 f2bf(float f) {
    union { float f; unsigned int i; } v;
    v.f = f;
    unsigned int x = v.i;
    unsigned int r = (x + 0x7fffu + ((x >> 16) & 1u)) >> 16;
    return (u16)r;
}

// ---------------- prep: cast x to bf16 ----------------
__global__ __launch_bounds__(256) void cast_x_k(const float* __restrict__ x,
                                                u16* __restrict__ xb) {
    int i = blockIdx.x * 256 + threadIdx.x;   // 4 elems/thread
    float4v v = ((const float4v*)x)[i];
    ushort4 o;
    o.x = f2bf(v[0]); o.y = f2bf(v[1]); o.z = f2bf(v[2]); o.w = f2bf(v[3]);
    ((ushort4*)xb)[i] = o;
}

// ---------------- prep: cast + transpose weights (K,N)->(N,K) bf16 ----------------
__global__ __launch_bounds__(256) void transw_k(const float* __restrict__ Wq,
                                                const float* __restrict__ Wk,
                                                const float* __restrict__ Wv,
                                                const float* __restrict__ Wo,
                                                u16* __restrict__ WT) {
    __shared__ u16 t[32][33];
    int wsel = blockIdx.z;
    const float* W = (wsel == 0) ? Wq : (wsel == 1) ? Wk : (wsel == 2) ? Wv : Wo;
    u16* o = WT + (size_t)wsel * DD * DD;
    int k0 = blockIdx.y * 32, n0 = blockIdx.x * 32;
    int tx = threadIdx.x, ty = threadIdx.y;   // 32 x 8
#pragma unroll
    for (int i = 0; i < 4; i++) {
        int k = ty + i * 8;
        t[k][tx] = f2bf(W[(size_t)(k0 + k) * DD + n0 + tx]);
    }
    __syncthreads();
#pragma unroll
    for (int i = 0; i < 4; i++) {
        int n = ty + i * 8;
        o[(size_t)(n0 + n) * DD + k0 + tx] = t[tx][n];
    }
}

// ---------------- GEMM (r11 winner, unchanged): BK=64, XOR-swizzled, reg-prefetch ------------
template <int MODE, int TM, int TN>
__global__ __launch_bounds__(256) void gemm_k(const u16* __restrict__ A,
                                              const u16* __restrict__ WT0,
                                              void* __restrict__ outp) {
    const int K = DD, BK = 64;
    const int MT = TM / 32, NT = TN / 32;
    const int NS = (TM + TN) * (BK / 8) / 256;

    int z = blockIdx.z;
    const u16* WT = WT0 + (size_t)z * DD * DD;
    int n0 = blockIdx.x * TN, m0 = blockIdx.y * TM;

    __shared__ u16 S[(TM + TN) * BK];

    int tid = threadIdx.x;
    int lane = tid & 63, w = tid >> 6;
    int wm = (w >> 1) * (TM / 2), wn = (w & 1) * (TN / 2);
    int quad = lane >> 4, l16 = lane & 15;

    const u16* gp[NS];
    u16* lp[NS];
#pragma unroll
    for (int j = 0; j < NS; j++) {
        int cid = tid + j * 256;
        int r = cid >> 3, c = cid & 7;
        lp[j] = S + r * BK + (c ^ (r & 7)) * 8;
        gp[j] = (r < TM ? A + (size_t)(m0 + r) * K
                        : WT + (size_t)(n0 + r - TM) * K) + c * 8;
    }
    int swz = l16 & 7;

    float4v acc[MT][NT];
#pragma unroll
    for (int i = 0; i < MT; i++)
#pragma unroll
        for (int j = 0; j < NT; j++) acc[i][j] = (float4v)(0.0f);

    short8 pr[NS];
#pragma unroll
    for (int j = 0; j < NS; j++) pr[j] = *(const short8*)gp[j];

    const int NK = K / BK;
#pragma unroll 1
    for (int ki = 0; ki < NK; ki++) {
        __syncthreads();
#pragma unroll
        for (int j = 0; j < NS; j++) *(short8*)lp[j] = pr[j];
        __syncthreads();

        if (ki + 1 < NK) {
            int k0 = (ki + 1) * BK;
#pragma unroll
            for (int j = 0; j < NS; j++) pr[j] = *(const short8*)(gp[j] + k0);
        }

#pragma unroll
        for (int ks = 0; ks < 2; ks++) {
            int cq = ((ks * 4 + quad) ^ swz) * 8;
            short8 a[MT], b[NT];
#pragma unroll
            for (int mt = 0; mt < MT; mt++)
                a[mt] = *(const short8*)&S[(wm + mt * 16 + l16) * BK + cq];
#pragma unroll
            for (int nt = 0; nt < NT; nt++)
                b[nt] = *(const short8*)&S[(TM + wn + nt * 16 + l16) * BK + cq];
#pragma unroll
            for (int mt = 0; mt < MT; mt++)
#pragma unroll
                for (int nt = 0; nt < NT; nt++)
                    acc[mt][nt] = __builtin_amdgcn_mfma_f32_16x16x32_bf16(
                        a[mt], b[nt], acc[mt][nt], 0, 0, 0);
        }
    }

#pragma unroll
    for (int mt = 0; mt < MT; mt++) {
#pragma unroll
        for (int nt = 0; nt < NT; nt++) {
#pragma unroll
            for (int r = 0; r < 4; r++) {
                int m = m0 + wm + mt * 16 + quad * 4 + r;
                int n = n0 + wn + nt * 16 + l16;
                float v = acc[mt][nt][r];
                if constexpr (MODE == 0) {
                    int bb = m >> 11, t = m & 2047;
                    int h = n >> 6, dh = n & 63;
                    size_t idx;
                    if (z == 2)   // V stored transposed: (b,h,dh,t)
                        idx = (((size_t)2 * BB * HH + bb * HH + h) * DHD + dh) * TT + t;
                    else
                        idx = (((size_t)z * BB * HH + bb * HH + h) * TT + t) * DHD + dh;
                    ((u16*)outp)[idx] = f2bf(v);
                } else {
                    ((float*)outp)[(size_t)m * DD + n] = v;
                }
            }
        }
    }
}

// ---------------- flash attention: r12 structure (best measured) + raw v_exp_f32 ------------
// r12 operating point: 512 thr, merged pair p / 31-p, 16 waves/CU, 1 KV tile per
// barrier-round, XOR-swizzled unpadded LDS (0-conflict family), S^T trick,
// no-max softmax. Single change vs r12: exp2f -> __builtin_amdgcn_exp2f
// (raw v_exp_f32; libm exp2f costs ~5-6 VALU insts in fixups, and 16 calls/tile
// made it the largest VALU block in the issue-bound accounting). Args are in
// [-30000, ~15]: v_exp flushes the mask to exact 0, ~1ulp elsewhere.
__global__ __launch_bounds__(512) void attn_k(const u16* __restrict__ QKV,
                                              u16* __restrict__ AO) {
    const u16* Q  = QKV;
    const u16* Kp = QKV + (size_t)MM * DD;
    const u16* Vp = QKV + (size_t)2 * MM * DD;   // V^T: per head [DHD][TT]
    int bh = blockIdx.y;
    int tswz = (blockIdx.x + blockIdx.y) & 15;
    int p = (blockIdx.y & 16) ? (15 - tswz) : tswz;
    int qA = p, qB = 31 - p;
    size_t hoff = (size_t)bh * TT * DHD;

    __shared__ u16 Qs[2][64 * 64];
    __shared__ u16 Ks[2][64 * 64];
    __shared__ u16 VTs[2][64 * 64];
    __shared__ u16 Ps[8][16 * 64];

    int tid = threadIdx.x;
    int lane = tid & 63, wv = tid >> 6;      // 8 waves
    int g = wv >> 2, w4 = wv & 3;            // group (phase), 16-row block
    int quad = lane >> 4, l16 = lane & 15;

    // staging: one 16B chunk per thread per 64x64 tile
    int sr = tid >> 3, sc = tid & 7;
    int sl = sr * 64 + ((sc ^ (sr & 7)) * 8);
    const u16* gK = Kp + hoff + (size_t)sr * DHD + sc * 8;
    const u16* gV = Vp + hoff + (size_t)sr * TT + sc * 8;

    // stage both Q tiles, scaled by (1/sqrt(DH)) * log2(e)
    const float qscale = 0.125f * 1.4426950408889634f;
#pragma unroll
    for (int t = 0; t < 2; t++) {
        int q0 = (t ? qB : qA) * 64;
        short8 v = *(const short8*)(Q + hoff + (size_t)(q0 + sr) * DHD + sc * 8);
        short8 sv;
#pragma unroll
        for (int e = 0; e < 8; e++) sv[e] = (short)f2bf(bf2f((u16)v[e]) * qscale);
        *(short8*)&Qs[t][sl] = sv;
    }

    short8 prK = *(const short8*)gK;   // prefetch KV tile 0
    short8 prV = *(const short8*)gV;

    __syncthreads();   // Q staged
    int cxs = l16 & 7;
    int fr = w4 * 16 + l16;   // my q-row within my tile
    short8 aq0 = *(const short8*)&Qs[g][fr * 64 + ((quad ^ cxs) * 8)];
    short8 aq1 = *(const short8*)&Qs[g][fr * 64 + (((4 + quad) ^ cxs) * 8)];

    int myqt = g ? qB : qA;
    int ntile = myqt + 1;     // my compute-active rounds
    int NR = qB + 1;          // total rounds (B's range covers A's)

    float4v o[4];
#pragma unroll
    for (int i = 0; i < 4; i++) o[i] = (float4v)(0.0f);
    float lr = 0.0f;

#pragma unroll 1
    for (int jt = 0; jt < NR; jt++) {
        int db = jt & 1;
        *(short8*)&Ks[db][sl]  = prK;
        *(short8*)&VTs[db][sl] = prV;
        __syncthreads();

        if (jt + 1 < NR) {   // prefetch next KV tile; in flight under compute
            size_t nj = (size_t)(jt + 1) * 64;
            prK = *(const short8*)(gK + nj * DHD);
            prV = *(const short8*)(gV + nj);
        }

        if (jt < ntile) {
            // S^T (64 kv x 16 q per wave) = K·Q^T
            float4v s[4];
#pragma unroll
            for (int ct = 0; ct < 4; ct++) {
                int kr = (ct * 16 + l16) * 64;
                short8 ak0 = *(const short8*)&Ks[db][kr + ((quad ^ cxs) * 8)];
                short8 ak1 = *(const short8*)&Ks[db][kr + (((4 + quad) ^ cxs) * 8)];
                float4v sv = (float4v)(0.0f);
                sv = __builtin_amdgcn_mfma_f32_16x16x32_bf16(ak0, aq0, sv, 0, 0, 0);
                sv = __builtin_amdgcn_mfma_f32_16x16x32_bf16(ak1, aq1, sv, 0, 0, 0);
                s[ct] = sv;   // lane: kv = ct*16+quad*4+r, q = fr
            }

            if (jt == myqt) {   // diagonal tile: mask kv > q (local coords)
                int ql = w4 * 16 + l16;
#pragma unroll
                for (int ct = 0; ct < 4; ct++)
#pragma unroll
                    for (int r = 0; r < 4; r++) {
                        int kvl = ct * 16 + quad * 4 + r;
                        if (kvl > ql) s[ct][r] = -30000.0f;
                    }
            }

            // p = v_exp_f32(s); P write (C->A layout) as swizzled 8B stores
#pragma unroll
            for (int ct = 0; ct < 4; ct++) {
                float p0 = __builtin_amdgcn_exp2f(s[ct][0]);
                float p1 = __builtin_amdgcn_exp2f(s[ct][1]);
                float p2 = __builtin_amdgcn_exp2f(s[ct][2]);
                float p3 = __builtin_amdgcn_exp2f(s[ct][3]);
                lr += (p0 + p1) + (p2 + p3);
                union { float f; unsigned u; } c0, c1, c2, c3;
                c0.f = p0; c1.f = p1; c2.f = p2; c3.f = p3;
                ushort4 pw;
                pw.x = (u16)(c0.u >> 16);
                pw.y = (u16)(c1.u >> 16);
                pw.z = (u16)(c2.u >> 16);
                pw.w = (u16)(c3.u >> 16);
                int chnk = (ct * 2 + (quad >> 1)) ^ cxs;
                *(ushort4*)&Ps[wv][l16 * 64 + chnk * 8 + (quad & 1) * 4] = pw;
            }

            short8 ap0 = *(const short8*)&Ps[wv][l16 * 64 + ((quad ^ cxs) * 8)];
            short8 ap1 = *(const short8*)&Ps[wv][l16 * 64 + (((4 + quad) ^ cxs) * 8)];
#pragma unroll
            for (int ct = 0; ct < 4; ct++) {
                int vr = (ct * 16 + l16) * 64;
                short8 bv0 = *(const short8*)&VTs[db][vr + ((quad ^ cxs) * 8)];
                short8 bv1 = *(const short8*)&VTs[db][vr + (((4 + quad) ^ cxs) * 8)];
                o[ct] = __builtin_amdgcn_mfma_f32_16x16x32_bf16(ap0, bv0, o[ct], 0, 0, 0);
                o[ct] = __builtin_amdgcn_mfma_f32_16x16x32_bf16(ap1, bv1, o[ct], 0, 0, 0);
            }
        }
    }

    // reduce row sums across quads (lane holds q = w4*16 + l16)
    float rs = lr;
    rs += __shfl_xor(rs, 16);
    rs += __shfl_xor(rs, 32);
    int gbase = lane & 48;
    float rinv[4];
#pragma unroll
    for (int r = 0; r < 4; r++)
        rinv[r] = 1.0f / __shfl(rs, gbase + quad * 4 + r);

    int b = bh >> 4, h = bh & 15;
    int q0 = myqt * 64;
#pragma unroll
    for (int ct = 0; ct < 4; ct++) {
#pragma unroll
        for (int r = 0; r < 4; r++) {
            int q = q0 + w4 * 16 + quad * 4 + r;
            int d = h * 64 + ct * 16 + l16;
            AO[(size_t)(b * TT + q) * DD + d] = f2bf(o[ct][r] * rinv[r]);
        }
    }
}

extern "C" void kernel_launch(void* const* d_in, const int* in_sizes, int n_in,
                              void* d_out, int out_size, void* d_ws, size_t ws_size,
                              hipStream_t stream) {
    const float* x  = (const float*)d_in[0];
    const float* Wq = (const float*)d_in[1];
    const float* Wk = (const float*)d_in[2];
    const float* Wv = (const float*)d_in[3];
    const float* Wo = (const float*)d_in[4];

    u16* xb  = (u16*)d_ws;                       // 8 MB  : x in bf16
    u16* WT  = xb + (size_t)MM * DD;             // 8 MB  : 4 transposed weights bf16
    u16* QKV = WT + (size_t)4 * DD * DD;         // 24 MB : Q,K (b,h,t,dh) + V^T (b,h,dh,t)
    u16* AO  = QKV + (size_t)3 * MM * DD;        // 8 MB  : attention out (B,T,D) bf16
    float* out = (float*)d_out;

    cast_x_k<<<dim3(MM * DD / 1024), 256, 0, stream>>>(x, xb);
    transw_k<<<dim3(32, 32, 4), dim3(32, 8), 0, stream>>>(Wq, Wk, Wv, Wo, WT);
    gemm_k<0, 128, 128><<<dim3(DD / 128, MM / 128, 3), 256, 0, stream>>>(xb, WT, QKV);
    attn_k<<<dim3(16, 32), 512, 0, stream>>>(QKV, AO);
    gemm_k<1, 64, 128><<<dim3(DD / 128, MM / 64, 1), 256, 0, stream>>>(AO, WT + (size_t)3 * DD * DD, out);
}